// Round 1
// baseline (136.437 us; speedup 1.0000x reference)
//
#include <hip/hip_runtime.h>

// VectorQuantizer: x[8,4,32,32] f32, codebook[16384,4] f32
// outputs concat: out[32768] f32, loss[1] f32, idx[8192] (written as f32)
//
// Row n = b*1024 + h*32 + w  (b = n>>10, p = n&1023)
// z[n][c] = x[b*4096 + c*1024 + p]
// d[n][k] = (zz[n] + ee[k]) - 2*dot  -- exact fp32 replication of
//   np: sum(z*z,1,keepdims) + sum(e*e,1) - 2*matmul(z, e.T)
// argmin ties resolve to smallest k (np first-occurrence semantics).

#define NUM_VOCAB 16384
#define NROWS 8192
#define NELEM 32768
#define CHUNK 512            // codes per wave in argmin kernel

// ws layout:
//   [0, 64KB)        : ee (16384 f32)
//   [64KB, 128KB)    : packed u64 per row (8192)  -- (d_bits<<32)|k
//   [128KB, 128KB+8) : double loss accumulator

__global__ __launch_bounds__(256) void k_init(const float* __restrict__ cb,
                                              float* __restrict__ ee,
                                              unsigned long long* __restrict__ packed,
                                              double* __restrict__ accum) {
    int i = blockIdx.x * 256 + threadIdx.x;
    if (i < NUM_VOCAB) {
        float e0 = cb[i * 4 + 0], e1 = cb[i * 4 + 1];
        float e2 = cb[i * 4 + 2], e3 = cb[i * 4 + 3];
        // numpy sum over axis=1 (n<8 path): sequential, no FMA contraction
        float s = __fadd_rn(__fadd_rn(__fadd_rn(__fmul_rn(e0, e0),
                                                __fmul_rn(e1, e1)),
                                      __fmul_rn(e2, e2)),
                            __fmul_rn(e3, e3));
        ee[i] = s;
    }
    if (i < NROWS) packed[i] = 0xFFFFFFFFFFFFFFFFULL;
    if (i == 0) *accum = 0.0;
}

__global__ __launch_bounds__(256) void k_argmin(const float* __restrict__ x,
                                                const float* __restrict__ cb,
                                                const float* __restrict__ ee,
                                                unsigned long long* __restrict__ packed) {
    const int lane = threadIdx.x & 63;
    const int wave = threadIdx.x >> 6;          // 0..3
    const int tile = blockIdx.x;                // 0..127 (64 rows each)
    const int cg   = blockIdx.y;                // 0..7
    const int row  = tile * 64 + lane;
    const int k0   = (cg * 4 + wave) * CHUNK;   // code chunk start

    const int b = row >> 10, p = row & 1023;
    const float* xb = x + b * 4096 + p;
    const float z0 = xb[0], z1 = xb[1024], z2 = xb[2048], z3 = xb[3072];
    // zz: sequential square-adds, no contraction (matches np)
    const float zz = __fadd_rn(__fadd_rn(__fadd_rn(__fmul_rn(z0, z0),
                                                   __fmul_rn(z1, z1)),
                                         __fmul_rn(z2, z2)),
                               __fmul_rn(z3, z3));

    float best = 3.4e38f;
    int   bk   = 0;
    const float4* cb4 = (const float4*)cb;
#pragma unroll 4
    for (int k = k0; k < k0 + CHUNK; ++k) {
        const float4 e  = cb4[k];      // wave-uniform -> s_load
        const float eek = ee[k];       // wave-uniform -> s_load
        // dot: sequential fma chain (rounding diff vs BLAS is ~1e-11, far
        // below the 2.4e-7 quantization granularity of the final subtract)
        float dot = __builtin_fmaf(z3, e.w,
                    __builtin_fmaf(z2, e.z,
                    __builtin_fmaf(z1, e.y, __fmul_rn(z0, e.x))));
        float t = __fadd_rn(zz, eek);              // np: (zz + ee[k])
        float d = __builtin_fmaf(-2.0f, dot, t);   // == round(t - 2*dot); 2*dot exact
        if (d < best) { best = d; bk = k; }        // strict < : first-index ties
    }
    // d > 0 always (min ||z||^2 ~ 0.03 >> codebook scale) -> float bits monotone.
    unsigned long long key =
        ((unsigned long long)__float_as_uint(best) << 32) | (unsigned)bk;
    atomicMin(&packed[row], key);
}

__global__ __launch_bounds__(256) void k_final(const float* __restrict__ x,
                                               const float* __restrict__ cb,
                                               const unsigned long long* __restrict__ packed,
                                               float* __restrict__ out,
                                               double* __restrict__ accum) {
    const int n = blockIdx.x * 256 + threadIdx.x;   // 0..8191
    const int b = n >> 10, p = n & 1023;
    const float* xb = x + b * 4096 + p;
    const float z0 = xb[0], z1 = xb[1024], z2 = xb[2048], z3 = xb[3072];

    const int k = (int)(unsigned)(packed[n] & 0xFFFFFFFFULL);
    const float e0 = cb[k * 4 + 0], e1 = cb[k * 4 + 1];
    const float e2 = cb[k * 4 + 2], e3 = cb[k * 4 + 3];

    // out = embed, transposed back to [B,C,H,W]
    float* ob = out + b * 4096 + p;
    ob[0] = e0; ob[1024] = e1; ob[2048] = e2; ob[3072] = e3;
    // idx written as float (harness reads whole buffer as f32)
    out[NELEM + 1 + n] = (float)k;

    const float d0 = e0 - z0, d1 = e1 - z1, d2 = e2 - z2, d3 = e3 - z3;
    double v = (double)d0 * d0 + (double)d1 * d1 + (double)d2 * d2 + (double)d3 * d3;

    // wave reduce (64 lanes) then cross-wave via LDS
    for (int o = 32; o > 0; o >>= 1) v += __shfl_down(v, o);
    __shared__ double sred[4];
    if ((threadIdx.x & 63) == 0) sred[threadIdx.x >> 6] = v;
    __syncthreads();
    if (threadIdx.x == 0) {
        double t = sred[0] + sred[1] + sred[2] + sred[3];
        atomicAdd(accum, t);
    }
}

__global__ void k_loss(const double* __restrict__ accum, float* __restrict__ out) {
    float m = (float)(*accum / (double)NELEM);
    out[NELEM] = m + 0.25f * m;   // both stop-gradient terms equal in forward
}

extern "C" void kernel_launch(void* const* d_in, const int* in_sizes, int n_in,
                              void* d_out, int out_size, void* d_ws, size_t ws_size,
                              hipStream_t stream) {
    const float* x  = (const float*)d_in[0];   // 32768
    const float* cb = (const float*)d_in[1];   // 65536
    float* out = (float*)d_out;                // 40961

    char* w = (char*)d_ws;
    float* ee = (float*)w;
    unsigned long long* packed = (unsigned long long*)(w + 65536);
    double* accum = (double*)(w + 131072);

    k_init<<<dim3(NUM_VOCAB / 256), dim3(256), 0, stream>>>(cb, ee, packed, accum);
    k_argmin<<<dim3(NROWS / 64, (NUM_VOCAB / CHUNK) / 4), dim3(256), 0, stream>>>(
        x, cb, ee, packed);
    k_final<<<dim3(NROWS / 256), dim3(256), 0, stream>>>(x, cb, packed, out, accum);
    k_loss<<<dim3(1), dim3(1), 0, stream>>>(accum, out);
}

// Round 2
// 101.061 us; speedup vs baseline: 1.3500x; 1.3500x over previous
//
#include <hip/hip_runtime.h>

// VectorQuantizer: x[8,4,32,32] f32, codebook[16384,4] f32
// outputs concat: out[32768] f32, loss[1] f32, idx[8192] (as f32)
//
// Row n = b*1024 + p  (b = n>>10, p = n&1023); z[n][c] = x[b*4096 + c*1024 + p]
// d[n][k] = (zz[n] + ee[k]) - 2*dot, fp32 rounding replicated exactly:
//   zz/ee: sequential non-contracted square-adds; dot: sequential FMA chain;
//   t = __fadd_rn(zz,ee); d = fmaf(-2,dot,t). Strict-< ascending-k scan =
//   numpy first-index ties. DO NOT perturb this arithmetic (idx ties).
//
// R2: argmin restructured — codebook reads wave-uniform (scalar s_load path),
// 4 rows per lane (4x load amortization, ILP=4). Grid 32x16 blocks, 4 waves,
// 256 codes/wave.

#define NUM_VOCAB 16384
#define NROWS 8192
#define NELEM 32768
#define CODES_PER_WAVE 256
#define ROWS_PER_LANE 4

// ws layout:
//   [0, 64KB)        : ee (16384 f32)
//   [64KB, 128KB)    : packed u64 per row (8192)  -- (d_bits<<32)|k
//   [128KB, 128KB+8) : double loss accumulator

__global__ __launch_bounds__(256) void k_init(const float* __restrict__ cb,
                                              float* __restrict__ ee,
                                              unsigned long long* __restrict__ packed,
                                              double* __restrict__ accum) {
    int i = blockIdx.x * 256 + threadIdx.x;
    if (i < NUM_VOCAB) {
        float e0 = cb[i * 4 + 0], e1 = cb[i * 4 + 1];
        float e2 = cb[i * 4 + 2], e3 = cb[i * 4 + 3];
        float s = __fadd_rn(__fadd_rn(__fadd_rn(__fmul_rn(e0, e0),
                                                __fmul_rn(e1, e1)),
                                      __fmul_rn(e2, e2)),
                            __fmul_rn(e3, e3));
        ee[i] = s;
    }
    if (i < NROWS) packed[i] = 0xFFFFFFFFFFFFFFFFULL;
    if (i == 0) *accum = 0.0;
}

__global__ __launch_bounds__(256) void k_argmin(const float* __restrict__ x,
                                                const float* __restrict__ cb,
                                                const float* __restrict__ ee,
                                                unsigned long long* __restrict__ packed) {
    const int lane = threadIdx.x & 63;
    // wave id made provably wave-uniform so codebook indexing scalarizes
    const int wave = __builtin_amdgcn_readfirstlane(threadIdx.x >> 6); // 0..3
    const int tile = blockIdx.x;                 // 0..31 (256 rows each)
    const int cg   = blockIdx.y;                 // 0..15
    const int k0   = (cg * 4 + wave) * CODES_PER_WAVE;

    // 4 rows per lane: row_r = tile*256 + r*64 + lane
    float z0[ROWS_PER_LANE], z1[ROWS_PER_LANE], z2[ROWS_PER_LANE], z3[ROWS_PER_LANE];
    float zz[ROWS_PER_LANE];
#pragma unroll
    for (int r = 0; r < ROWS_PER_LANE; ++r) {
        const int row = tile * 256 + r * 64 + lane;
        const int b = row >> 10, p = row & 1023;
        const float* xb = x + b * 4096 + p;
        z0[r] = xb[0]; z1[r] = xb[1024]; z2[r] = xb[2048]; z3[r] = xb[3072];
        zz[r] = __fadd_rn(__fadd_rn(__fadd_rn(__fmul_rn(z0[r], z0[r]),
                                              __fmul_rn(z1[r], z1[r])),
                                    __fmul_rn(z2[r], z2[r])),
                          __fmul_rn(z3[r], z3[r]));
    }

    float best[ROWS_PER_LANE];
    int   bk[ROWS_PER_LANE];
#pragma unroll
    for (int r = 0; r < ROWS_PER_LANE; ++r) { best[r] = 3.4e38f; bk[r] = 0; }

    const float4* cb4 = (const float4*)cb;
#pragma unroll 8
    for (int kk = 0; kk < CODES_PER_WAVE; ++kk) {
        const int k = k0 + kk;                 // wave-uniform -> s_load path
        const float4 e  = cb4[k];
        const float eek = ee[k];
#pragma unroll
        for (int r = 0; r < ROWS_PER_LANE; ++r) {
            float dot = __builtin_fmaf(z3[r], e.w,
                        __builtin_fmaf(z2[r], e.z,
                        __builtin_fmaf(z1[r], e.y, __fmul_rn(z0[r], e.x))));
            float t = __fadd_rn(zz[r], eek);
            float d = __builtin_fmaf(-2.0f, dot, t);
            if (d < best[r]) { best[r] = d; bk[r] = k; }  // strict <: first-index
        }
    }

    // d > 0 always here -> float bits monotone; low32=k makes ties pick min k.
#pragma unroll
    for (int r = 0; r < ROWS_PER_LANE; ++r) {
        const int row = tile * 256 + r * 64 + lane;
        unsigned long long key =
            ((unsigned long long)__float_as_uint(best[r]) << 32) | (unsigned)bk[r];
        atomicMin(&packed[row], key);
    }
}

__global__ __launch_bounds__(256) void k_final(const float* __restrict__ x,
                                               const float* __restrict__ cb,
                                               const unsigned long long* __restrict__ packed,
                                               float* __restrict__ out,
                                               double* __restrict__ accum) {
    const int n = blockIdx.x * 256 + threadIdx.x;   // 0..8191
    const int b = n >> 10, p = n & 1023;
    const float* xb = x + b * 4096 + p;
    const float z0 = xb[0], z1 = xb[1024], z2 = xb[2048], z3 = xb[3072];

    const int k = (int)(unsigned)(packed[n] & 0xFFFFFFFFULL);
    const float e0 = cb[k * 4 + 0], e1 = cb[k * 4 + 1];
    const float e2 = cb[k * 4 + 2], e3 = cb[k * 4 + 3];

    float* ob = out + b * 4096 + p;
    ob[0] = e0; ob[1024] = e1; ob[2048] = e2; ob[3072] = e3;
    out[NELEM + 1 + n] = (float)k;

    const float d0 = e0 - z0, d1 = e1 - z1, d2 = e2 - z2, d3 = e3 - z3;
    double v = (double)d0 * d0 + (double)d1 * d1 + (double)d2 * d2 + (double)d3 * d3;

    for (int o = 32; o > 0; o >>= 1) v += __shfl_down(v, o);
    __shared__ double sred[4];
    if ((threadIdx.x & 63) == 0) sred[threadIdx.x >> 6] = v;
    __syncthreads();
    if (threadIdx.x == 0) {
        double t = sred[0] + sred[1] + sred[2] + sred[3];
        atomicAdd(accum, t);
    }
}

__global__ void k_loss(const double* __restrict__ accum, float* __restrict__ out) {
    float m = (float)(*accum / (double)NELEM);
    out[NELEM] = m + 0.25f * m;
}

extern "C" void kernel_launch(void* const* d_in, const int* in_sizes, int n_in,
                              void* d_out, int out_size, void* d_ws, size_t ws_size,
                              hipStream_t stream) {
    const float* x  = (const float*)d_in[0];
    const float* cb = (const float*)d_in[1];
    float* out = (float*)d_out;

    char* w = (char*)d_ws;
    float* ee = (float*)w;
    unsigned long long* packed = (unsigned long long*)(w + 65536);
    double* accum = (double*)(w + 131072);

    k_init<<<dim3(NUM_VOCAB / 256), dim3(256), 0, stream>>>(cb, ee, packed, accum);
    k_argmin<<<dim3(NROWS / 256, NUM_VOCAB / (4 * CODES_PER_WAVE)), dim3(256), 0, stream>>>(
        x, cb, ee, packed);
    k_final<<<dim3(NROWS / 256), dim3(256), 0, stream>>>(x, cb, packed, out, accum);
    k_loss<<<dim3(1), dim3(1), 0, stream>>>(accum, out);
}

// Round 3
// 89.421 us; speedup vs baseline: 1.5258x; 1.1302x over previous
//
#include <hip/hip_runtime.h>

// VectorQuantizer: x[8,4,32,32] f32, codebook[16384,4] f32
// outputs concat: out[32768] f32, loss[1] f32, idx[8192] (as f32)
//
// Row n = b*1024 + p  (b = n>>10, p = n&1023); z[n][c] = x[b*4096 + c*1024 + p]
// d[n][k] = (zz[n] + ee[k]) - 2*dot, fp32 rounding replicated exactly:
//   zz/ee: sequential non-contracted square-adds; dot: sequential FMA chain;
//   t = __fadd_rn(zz,ee); d = fmaf(-2,dot,t). Strict-< ascending-k scan +
//   u64 (d_bits<<32)|k min = numpy first-index ties. DO NOT perturb (idx ties).
//
// R3: 2-kernel fusion. K1: 32 row-tiles x 16 code-groups, 512 thr (8 waves),
// 128 codes/wave, 4 rows/lane; ee computed per-block into LDS; cross-wave
// LDS merge -> one slot write per (cg,row). K2: slot-min + gather + out +
// loss, last-block writes loss scalar. No k_init, no global atomicMin.

#define NUM_VOCAB 16384
#define NROWS 8192
#define NELEM 32768
#define NCG 16               // code groups = slot count per row
#define CODES_PER_BLOCK 1024
#define CODES_PER_WAVE 128
#define ROWS_PER_LANE 4

// main ws layout:
//   [0, 1MB)      : slots u64 [NCG][NROWS]
//   [1MB, 1MB+8)  : double loss accumulator
//   [1MB+8, +12)  : u32 block counter for K2
#define SLOT_BYTES (NCG * NROWS * 8)
#define WS_MAIN_BYTES (SLOT_BYTES + 16)

__global__ __launch_bounds__(512, 4) void k_argmin(const float* __restrict__ x,
                                                   const float* __restrict__ cb,
                                                   unsigned long long* __restrict__ slots,
                                                   double* __restrict__ accum,
                                                   unsigned int* __restrict__ counter) {
    const int tid  = threadIdx.x;
    const int lane = tid & 63;
    const int wave = __builtin_amdgcn_readfirstlane(tid >> 6);  // 0..7, uniform
    const int tile = blockIdx.x;                 // 0..31 (256 rows)
    const int cg   = blockIdx.y;                 // 0..15 (1024 codes)

    if (tile == 0 && cg == 0 && tid == 0) { *accum = 0.0; *counter = 0u; }

    __shared__ float eeLDS[CODES_PER_BLOCK];                   // 4 KB
    __shared__ unsigned long long red[8][256];                 // 16 KB

    const float4* cb4 = (const float4*)cb;

    // stage ee for this block's 1024 codes (exact numpy rounding)
    for (int l = tid; l < CODES_PER_BLOCK; l += 512) {
        const float4 e = cb4[cg * CODES_PER_BLOCK + l];
        eeLDS[l] = __fadd_rn(__fadd_rn(__fadd_rn(__fmul_rn(e.x, e.x),
                                                 __fmul_rn(e.y, e.y)),
                                       __fmul_rn(e.z, e.z)),
                             __fmul_rn(e.w, e.w));
    }

    // load 4 rows/lane
    float z0[ROWS_PER_LANE], z1[ROWS_PER_LANE], z2[ROWS_PER_LANE], z3[ROWS_PER_LANE];
    float zz[ROWS_PER_LANE];
#pragma unroll
    for (int r = 0; r < ROWS_PER_LANE; ++r) {
        const int row = tile * 256 + r * 64 + lane;
        const int b = row >> 10, p = row & 1023;
        const float* xb = x + b * 4096 + p;
        z0[r] = xb[0]; z1[r] = xb[1024]; z2[r] = xb[2048]; z3[r] = xb[3072];
        zz[r] = __fadd_rn(__fadd_rn(__fadd_rn(__fmul_rn(z0[r], z0[r]),
                                              __fmul_rn(z1[r], z1[r])),
                                    __fmul_rn(z2[r], z2[r])),
                          __fmul_rn(z3[r], z3[r]));
    }
    __syncthreads();

    float best[ROWS_PER_LANE];
    int   bk[ROWS_PER_LANE];
#pragma unroll
    for (int r = 0; r < ROWS_PER_LANE; ++r) { best[r] = 3.4e38f; bk[r] = 0; }

    const int k0 = cg * CODES_PER_BLOCK + wave * CODES_PER_WAVE;
    const int l0 = wave * CODES_PER_WAVE;
#pragma unroll 8
    for (int kk = 0; kk < CODES_PER_WAVE; ++kk) {
        const int k = k0 + kk;                 // wave-uniform -> s_load path
        const float4 e  = cb4[k];
        const float eek = eeLDS[l0 + kk];      // uniform addr -> broadcast ds_read
#pragma unroll
        for (int r = 0; r < ROWS_PER_LANE; ++r) {
            float dot = __builtin_fmaf(z3[r], e.w,
                        __builtin_fmaf(z2[r], e.z,
                        __builtin_fmaf(z1[r], e.y, __fmul_rn(z0[r], e.x))));
            float t = __fadd_rn(zz[r], eek);
            float d = __builtin_fmaf(-2.0f, dot, t);
            if (d < best[r]) { best[r] = d; bk[r] = k; }  // strict <: first-index
        }
    }

    // d > 0 always here -> float bits monotone; low32=k: ties pick min k.
#pragma unroll
    for (int r = 0; r < ROWS_PER_LANE; ++r) {
        red[wave][r * 64 + lane] =
            ((unsigned long long)__float_as_uint(best[r]) << 32) | (unsigned)bk[r];
    }
    __syncthreads();

    if (tid < 256) {
        unsigned long long m = red[0][tid];
#pragma unroll
        for (int w2 = 1; w2 < 8; ++w2) {
            unsigned long long s = red[w2][tid];
            if (s < m) m = s;
        }
        slots[cg * NROWS + tile * 256 + tid] = m;
    }
}

__global__ __launch_bounds__(256) void k_final(const float* __restrict__ x,
                                               const float* __restrict__ cb,
                                               const unsigned long long* __restrict__ slots,
                                               float* __restrict__ out,
                                               double* __restrict__ accum,
                                               unsigned int* __restrict__ counter) {
    const int n = blockIdx.x * 256 + threadIdx.x;   // 0..8191

    unsigned long long m = slots[n];
#pragma unroll
    for (int cg = 1; cg < NCG; ++cg) {
        unsigned long long s = slots[cg * NROWS + n];
        if (s < m) m = s;
    }
    const int k = (int)(unsigned)(m & 0xFFFFFFFFULL);

    const int b = n >> 10, p = n & 1023;
    const float* xb = x + b * 4096 + p;
    const float z0 = xb[0], z1 = xb[1024], z2 = xb[2048], z3 = xb[3072];
    const float e0 = cb[k * 4 + 0], e1 = cb[k * 4 + 1];
    const float e2 = cb[k * 4 + 2], e3 = cb[k * 4 + 3];

    float* ob = out + b * 4096 + p;
    ob[0] = e0; ob[1024] = e1; ob[2048] = e2; ob[3072] = e3;
    out[NELEM + 1 + n] = (float)k;

    const float d0 = e0 - z0, d1 = e1 - z1, d2 = e2 - z2, d3 = e3 - z3;
    double v = (double)d0 * d0 + (double)d1 * d1 + (double)d2 * d2 + (double)d3 * d3;

    for (int o = 32; o > 0; o >>= 1) v += __shfl_down(v, o);
    __shared__ double sred[4];
    if ((threadIdx.x & 63) == 0) sred[threadIdx.x >> 6] = v;
    __syncthreads();
    if (threadIdx.x == 0) {
        atomicAdd(accum, sred[0] + sred[1] + sred[2] + sred[3]);
        __threadfence();
        unsigned int prev = atomicAdd(counter, 1u);
        if (prev == (NROWS / 256) - 1) {          // last block
            __threadfence();
            double tot = atomicAdd(accum, 0.0);   // forced coherent read
            float mloss = (float)(tot / (double)NELEM);
            out[NELEM] = mloss + 0.25f * mloss;
        }
    }
}

// ---------- fallback path (R2-proven) if ws is too small for slots ----------

__global__ __launch_bounds__(256) void fb_init(const float* __restrict__ cb,
                                               float* __restrict__ ee,
                                               unsigned long long* __restrict__ packed,
                                               double* __restrict__ accum) {
    int i = blockIdx.x * 256 + threadIdx.x;
    if (i < NUM_VOCAB) {
        float e0 = cb[i * 4 + 0], e1 = cb[i * 4 + 1];
        float e2 = cb[i * 4 + 2], e3 = cb[i * 4 + 3];
        ee[i] = __fadd_rn(__fadd_rn(__fadd_rn(__fmul_rn(e0, e0),
                                              __fmul_rn(e1, e1)),
                                    __fmul_rn(e2, e2)),
                          __fmul_rn(e3, e3));
    }
    if (i < NROWS) packed[i] = 0xFFFFFFFFFFFFFFFFULL;
    if (i == 0) *accum = 0.0;
}

__global__ __launch_bounds__(256) void fb_argmin(const float* __restrict__ x,
                                                 const float* __restrict__ cb,
                                                 const float* __restrict__ ee,
                                                 unsigned long long* __restrict__ packed) {
    const int lane = threadIdx.x & 63;
    const int wave = __builtin_amdgcn_readfirstlane(threadIdx.x >> 6);
    const int tile = blockIdx.x, cg = blockIdx.y;
    const int k0 = (cg * 4 + wave) * 256;

    float z0[4], z1[4], z2[4], z3[4], zz[4];
#pragma unroll
    for (int r = 0; r < 4; ++r) {
        const int row = tile * 256 + r * 64 + lane;
        const int b = row >> 10, p = row & 1023;
        const float* xb = x + b * 4096 + p;
        z0[r] = xb[0]; z1[r] = xb[1024]; z2[r] = xb[2048]; z3[r] = xb[3072];
        zz[r] = __fadd_rn(__fadd_rn(__fadd_rn(__fmul_rn(z0[r], z0[r]),
                                              __fmul_rn(z1[r], z1[r])),
                                    __fmul_rn(z2[r], z2[r])),
                          __fmul_rn(z3[r], z3[r]));
    }
    float best[4]; int bk[4];
#pragma unroll
    for (int r = 0; r < 4; ++r) { best[r] = 3.4e38f; bk[r] = 0; }
    const float4* cb4 = (const float4*)cb;
#pragma unroll 8
    for (int kk = 0; kk < 256; ++kk) {
        const int k = k0 + kk;
        const float4 e = cb4[k];
        const float eek = ee[k];
#pragma unroll
        for (int r = 0; r < 4; ++r) {
            float dot = __builtin_fmaf(z3[r], e.w,
                        __builtin_fmaf(z2[r], e.z,
                        __builtin_fmaf(z1[r], e.y, __fmul_rn(z0[r], e.x))));
            float t = __fadd_rn(zz[r], eek);
            float d = __builtin_fmaf(-2.0f, dot, t);
            if (d < best[r]) { best[r] = d; bk[r] = k; }
        }
    }
#pragma unroll
    for (int r = 0; r < 4; ++r) {
        const int row = tile * 256 + r * 64 + lane;
        unsigned long long key =
            ((unsigned long long)__float_as_uint(best[r]) << 32) | (unsigned)bk[r];
        atomicMin(&packed[row], key);
    }
}

__global__ __launch_bounds__(256) void fb_final(const float* __restrict__ x,
                                                const float* __restrict__ cb,
                                                const unsigned long long* __restrict__ packed,
                                                float* __restrict__ out,
                                                double* __restrict__ accum) {
    const int n = blockIdx.x * 256 + threadIdx.x;
    const int b = n >> 10, p = n & 1023;
    const float* xb = x + b * 4096 + p;
    const float z0 = xb[0], z1 = xb[1024], z2 = xb[2048], z3 = xb[3072];
    const int k = (int)(unsigned)(packed[n] & 0xFFFFFFFFULL);
    const float e0 = cb[k * 4 + 0], e1 = cb[k * 4 + 1];
    const float e2 = cb[k * 4 + 2], e3 = cb[k * 4 + 3];
    float* ob = out + b * 4096 + p;
    ob[0] = e0; ob[1024] = e1; ob[2048] = e2; ob[3072] = e3;
    out[NELEM + 1 + n] = (float)k;
    const float d0 = e0 - z0, d1 = e1 - z1, d2 = e2 - z2, d3 = e3 - z3;
    double v = (double)d0 * d0 + (double)d1 * d1 + (double)d2 * d2 + (double)d3 * d3;
    for (int o = 32; o > 0; o >>= 1) v += __shfl_down(v, o);
    __shared__ double sred[4];
    if ((threadIdx.x & 63) == 0) sred[threadIdx.x >> 6] = v;
    __syncthreads();
    if (threadIdx.x == 0) atomicAdd(accum, sred[0] + sred[1] + sred[2] + sred[3]);
}

__global__ void fb_loss(const double* __restrict__ accum, float* __restrict__ out) {
    float m = (float)(*accum / (double)NELEM);
    out[NELEM] = m + 0.25f * m;
}

extern "C" void kernel_launch(void* const* d_in, const int* in_sizes, int n_in,
                              void* d_out, int out_size, void* d_ws, size_t ws_size,
                              hipStream_t stream) {
    const float* x  = (const float*)d_in[0];
    const float* cb = (const float*)d_in[1];
    float* out = (float*)d_out;
    char* w = (char*)d_ws;

    if (ws_size >= (size_t)WS_MAIN_BYTES) {
        unsigned long long* slots = (unsigned long long*)w;
        double* accum = (double*)(w + SLOT_BYTES);
        unsigned int* counter = (unsigned int*)(w + SLOT_BYTES + 8);
        k_argmin<<<dim3(NROWS / 256, NCG), dim3(512), 0, stream>>>(
            x, cb, slots, accum, counter);
        k_final<<<dim3(NROWS / 256), dim3(256), 0, stream>>>(
            x, cb, slots, out, accum, counter);
    } else {
        float* ee = (float*)w;
        unsigned long long* packed = (unsigned long long*)(w + 65536);
        double* accum = (double*)(w + 131072);
        fb_init<<<dim3(NUM_VOCAB / 256), dim3(256), 0, stream>>>(cb, ee, packed, accum);
        fb_argmin<<<dim3(NROWS / 256, NUM_VOCAB / 1024), dim3(256), 0, stream>>>(
            x, cb, ee, packed);
        fb_final<<<dim3(NROWS / 256), dim3(256), 0, stream>>>(x, cb, packed, out, accum);
        fb_loss<<<dim3(1), dim3(1), 0, stream>>>(accum, out);
    }
}

// Round 4
// 85.797 us; speedup vs baseline: 1.5902x; 1.0422x over previous
//
#include <hip/hip_runtime.h>

// VectorQuantizer: x[8,4,32,32] f32, codebook[16384,4] f32
// outputs concat: out[32768] f32, loss[1] f32, idx[8192] (as f32)
//
// Row n = b*1024 + p  (b = n>>10, p = n&1023); z[n][c] = x[b*4096 + c*1024 + p]
// d[n][k] = (zz[n] + ee[k]) - 2*dot, fp32 rounding replicated exactly:
//   zz/ee: sequential non-contracted square-adds; dot: mul + sequential FMA
//   chain; t = add(zz,ee); d = fma(-2,dot,t). Strict-< ascending-k scan +
//   u64 (d_bits<<32)|k min = numpy first-index ties. DO NOT perturb (idx ties).
//
// R4: inner math packed into float2 ext-vectors -> v_pk_{mul,add,fma}_f32.
// Each packed component executes the identical scalar rounding chain, so
// results are bit-identical to R3; VALU instr count drops ~35%.
// Timing note: ~45us of every timed iteration is harness ws-poison fill
// (256MB @ ~6.7TB/s) + input restore — not addressable from kernel code.

#define NUM_VOCAB 16384
#define NROWS 8192
#define NELEM 32768
#define NCG 16               // code groups = slot count per row
#define CODES_PER_BLOCK 1024
#define CODES_PER_WAVE 128

typedef float v2f __attribute__((ext_vector_type(2)));

// main ws layout:
//   [0, 1MB)      : slots u64 [NCG][NROWS]
//   [1MB, 1MB+8)  : double loss accumulator
//   [1MB+8, +12)  : u32 block counter for K2
#define SLOT_BYTES (NCG * NROWS * 8)
#define WS_MAIN_BYTES (SLOT_BYTES + 16)

__global__ __launch_bounds__(512, 4) void k_argmin(const float* __restrict__ x,
                                                   const float* __restrict__ cb,
                                                   unsigned long long* __restrict__ slots,
                                                   double* __restrict__ accum,
                                                   unsigned int* __restrict__ counter) {
    const int tid  = threadIdx.x;
    const int lane = tid & 63;
    const int wave = __builtin_amdgcn_readfirstlane(tid >> 6);  // 0..7, uniform
    const int tile = blockIdx.x;                 // 0..31 (256 rows)
    const int cg   = blockIdx.y;                 // 0..15 (1024 codes)

    if (tile == 0 && cg == 0 && tid == 0) { *accum = 0.0; *counter = 0u; }

    __shared__ float eeLDS[CODES_PER_BLOCK];                   // 4 KB
    __shared__ unsigned long long red[8][256];                 // 16 KB

    const float4* cb4 = (const float4*)cb;

    // stage ee for this block's 1024 codes (exact numpy rounding)
    for (int l = tid; l < CODES_PER_BLOCK; l += 512) {
        const float4 e = cb4[cg * CODES_PER_BLOCK + l];
        eeLDS[l] = __fadd_rn(__fadd_rn(__fadd_rn(__fmul_rn(e.x, e.x),
                                                 __fmul_rn(e.y, e.y)),
                                       __fmul_rn(e.z, e.z)),
                             __fmul_rn(e.w, e.w));
    }

    // 4 rows/lane as 2 packed row-pairs: pair j holds rows r=2j (comp .x)
    // and r=2j+1 (comp .y); row r = tile*256 + r*64 + lane.
    v2f zA[2], zB[2], zC[2], zD[2], zz2[2];
#pragma unroll
    for (int j = 0; j < 2; ++j) {
#pragma unroll
        for (int i = 0; i < 2; ++i) {
            const int r = 2 * j + i;
            const int row = tile * 256 + r * 64 + lane;
            const int b = row >> 10, p = row & 1023;
            const float* xb = x + b * 4096 + p;
            const float z0 = xb[0], z1 = xb[1024], z2 = xb[2048], z3 = xb[3072];
            zA[j][i] = z0; zB[j][i] = z1; zC[j][i] = z2; zD[j][i] = z3;
            zz2[j][i] = __fadd_rn(__fadd_rn(__fadd_rn(__fmul_rn(z0, z0),
                                                      __fmul_rn(z1, z1)),
                                            __fmul_rn(z2, z2)),
                                  __fmul_rn(z3, z3));
        }
    }
    __syncthreads();

    float best[4];
    int   bk[4];
#pragma unroll
    for (int r = 0; r < 4; ++r) { best[r] = 3.4e38f; bk[r] = 0; }

    const int k0 = cg * CODES_PER_BLOCK + wave * CODES_PER_WAVE;
    const int l0 = wave * CODES_PER_WAVE;
    const v2f m2 = {-2.0f, -2.0f};
#pragma unroll 8
    for (int kk = 0; kk < CODES_PER_WAVE; ++kk) {
        const int k = k0 + kk;                 // wave-uniform -> s_load path
        const float4 e  = cb4[k];
        const float eek = eeLDS[l0 + kk];      // uniform addr -> broadcast ds_read
        const v2f ex = {e.x, e.x}, ey = {e.y, e.y};
        const v2f ez = {e.z, e.z}, ew = {e.w, e.w};
        const v2f eev = {eek, eek};
#pragma unroll
        for (int j = 0; j < 2; ++j) {
            // identical per-component chain: mul, fma, fma, fma
            v2f dot = __builtin_elementwise_fma(zD[j], ew,
                      __builtin_elementwise_fma(zC[j], ez,
                      __builtin_elementwise_fma(zB[j], ey, zA[j] * ex)));
            v2f t = zz2[j] + eev;                              // pk_add
            v2f d = __builtin_elementwise_fma(m2, dot, t);     // pk_fma
            if (d.x < best[2 * j])     { best[2 * j] = d.x;     bk[2 * j] = k; }
            if (d.y < best[2 * j + 1]) { best[2 * j + 1] = d.y; bk[2 * j + 1] = k; }
        }
    }

    // d > 0 always here -> float bits monotone; low32=k: ties pick min k.
#pragma unroll
    for (int r = 0; r < 4; ++r) {
        red[wave][r * 64 + lane] =
            ((unsigned long long)__float_as_uint(best[r]) << 32) | (unsigned)bk[r];
    }
    __syncthreads();

    if (tid < 256) {
        unsigned long long m = red[0][tid];
#pragma unroll
        for (int w2 = 1; w2 < 8; ++w2) {
            unsigned long long s = red[w2][tid];
            if (s < m) m = s;
        }
        slots[cg * NROWS + tile * 256 + tid] = m;
    }
}

__global__ __launch_bounds__(256) void k_final(const float* __restrict__ x,
                                               const float* __restrict__ cb,
                                               const unsigned long long* __restrict__ slots,
                                               float* __restrict__ out,
                                               double* __restrict__ accum,
                                               unsigned int* __restrict__ counter) {
    const int n = blockIdx.x * 256 + threadIdx.x;   // 0..8191

    unsigned long long m = slots[n];
#pragma unroll
    for (int cg = 1; cg < NCG; ++cg) {
        unsigned long long s = slots[cg * NROWS + n];
        if (s < m) m = s;
    }
    const int k = (int)(unsigned)(m & 0xFFFFFFFFULL);

    const int b = n >> 10, p = n & 1023;
    const float* xb = x + b * 4096 + p;
    const float z0 = xb[0], z1 = xb[1024], z2 = xb[2048], z3 = xb[3072];
    const float e0 = cb[k * 4 + 0], e1 = cb[k * 4 + 1];
    const float e2 = cb[k * 4 + 2], e3 = cb[k * 4 + 3];

    float* ob = out + b * 4096 + p;
    ob[0] = e0; ob[1024] = e1; ob[2048] = e2; ob[3072] = e3;
    out[NELEM + 1 + n] = (float)k;

    const float d0 = e0 - z0, d1 = e1 - z1, d2 = e2 - z2, d3 = e3 - z3;
    double v = (double)d0 * d0 + (double)d1 * d1 + (double)d2 * d2 + (double)d3 * d3;

    for (int o = 32; o > 0; o >>= 1) v += __shfl_down(v, o);
    __shared__ double sred[4];
    if ((threadIdx.x & 63) == 0) sred[threadIdx.x >> 6] = v;
    __syncthreads();
    if (threadIdx.x == 0) {
        atomicAdd(accum, sred[0] + sred[1] + sred[2] + sred[3]);
        __threadfence();
        unsigned int prev = atomicAdd(counter, 1u);
        if (prev == (NROWS / 256) - 1) {          // last block
            __threadfence();
            double tot = atomicAdd(accum, 0.0);   // forced coherent read
            float mloss = (float)(tot / (double)NELEM);
            out[NELEM] = mloss + 0.25f * mloss;
        }
    }
}

// ---------- fallback path (R2-proven) if ws is too small for slots ----------

__global__ __launch_bounds__(256) void fb_init(const float* __restrict__ cb,
                                               float* __restrict__ ee,
                                               unsigned long long* __restrict__ packed,
                                               double* __restrict__ accum) {
    int i = blockIdx.x * 256 + threadIdx.x;
    if (i < NUM_VOCAB) {
        float e0 = cb[i * 4 + 0], e1 = cb[i * 4 + 1];
        float e2 = cb[i * 4 + 2], e3 = cb[i * 4 + 3];
        ee[i] = __fadd_rn(__fadd_rn(__fadd_rn(__fmul_rn(e0, e0),
                                              __fmul_rn(e1, e1)),
                                    __fmul_rn(e2, e2)),
                          __fmul_rn(e3, e3));
    }
    if (i < NROWS) packed[i] = 0xFFFFFFFFFFFFFFFFULL;
    if (i == 0) *accum = 0.0;
}

__global__ __launch_bounds__(256) void fb_argmin(const float* __restrict__ x,
                                                 const float* __restrict__ cb,
                                                 const float* __restrict__ ee,
                                                 unsigned long long* __restrict__ packed) {
    const int lane = threadIdx.x & 63;
    const int wave = __builtin_amdgcn_readfirstlane(threadIdx.x >> 6);
    const int tile = blockIdx.x, cg = blockIdx.y;
    const int k0 = (cg * 4 + wave) * 256;

    float z0[4], z1[4], z2[4], z3[4], zz[4];
#pragma unroll
    for (int r = 0; r < 4; ++r) {
        const int row = tile * 256 + r * 64 + lane;
        const int b = row >> 10, p = row & 1023;
        const float* xb = x + b * 4096 + p;
        z0[r] = xb[0]; z1[r] = xb[1024]; z2[r] = xb[2048]; z3[r] = xb[3072];
        zz[r] = __fadd_rn(__fadd_rn(__fadd_rn(__fmul_rn(z0[r], z0[r]),
                                              __fmul_rn(z1[r], z1[r])),
                                    __fmul_rn(z2[r], z2[r])),
                          __fmul_rn(z3[r], z3[r]));
    }
    float best[4]; int bk[4];
#pragma unroll
    for (int r = 0; r < 4; ++r) { best[r] = 3.4e38f; bk[r] = 0; }
    const float4* cb4 = (const float4*)cb;
#pragma unroll 8
    for (int kk = 0; kk < 256; ++kk) {
        const int k = k0 + kk;
        const float4 e = cb4[k];
        const float eek = ee[k];
#pragma unroll
        for (int r = 0; r < 4; ++r) {
            float dot = __builtin_fmaf(z3[r], e.w,
                        __builtin_fmaf(z2[r], e.z,
                        __builtin_fmaf(z1[r], e.y, __fmul_rn(z0[r], e.x))));
            float t = __fadd_rn(zz[r], eek);
            float d = __builtin_fmaf(-2.0f, dot, t);
            if (d < best[r]) { best[r] = d; bk[r] = k; }
        }
    }
#pragma unroll
    for (int r = 0; r < 4; ++r) {
        const int row = tile * 256 + r * 64 + lane;
        unsigned long long key =
            ((unsigned long long)__float_as_uint(best[r]) << 32) | (unsigned)bk[r];
        atomicMin(&packed[row], key);
    }
}

__global__ __launch_bounds__(256) void fb_final(const float* __restrict__ x,
                                                const float* __restrict__ cb,
                                                const unsigned long long* __restrict__ packed,
                                                float* __restrict__ out,
                                                double* __restrict__ accum) {
    const int n = blockIdx.x * 256 + threadIdx.x;
    const int b = n >> 10, p = n & 1023;
    const float* xb = x + b * 4096 + p;
    const float z0 = xb[0], z1 = xb[1024], z2 = xb[2048], z3 = xb[3072];
    const int k = (int)(unsigned)(packed[n] & 0xFFFFFFFFULL);
    const float e0 = cb[k * 4 + 0], e1 = cb[k * 4 + 1];
    const float e2 = cb[k * 4 + 2], e3 = cb[k * 4 + 3];
    float* ob = out + b * 4096 + p;
    ob[0] = e0; ob[1024] = e1; ob[2048] = e2; ob[3072] = e3;
    out[NELEM + 1 + n] = (float)k;
    const float d0 = e0 - z0, d1 = e1 - z1, d2 = e2 - z2, d3 = e3 - z3;
    double v = (double)d0 * d0 + (double)d1 * d1 + (double)d2 * d2 + (double)d3 * d3;
    for (int o = 32; o > 0; o >>= 1) v += __shfl_down(v, o);
    __shared__ double sred[4];
    if ((threadIdx.x & 63) == 0) sred[threadIdx.x >> 6] = v;
    __syncthreads();
    if (threadIdx.x == 0) atomicAdd(accum, sred[0] + sred[1] + sred[2] + sred[3]);
}

__global__ void fb_loss(const double* __restrict__ accum, float* __restrict__ out) {
    float m = (float)(*accum / (double)NELEM);
    out[NELEM] = m + 0.25f * m;
}

extern "C" void kernel_launch(void* const* d_in, const int* in_sizes, int n_in,
                              void* d_out, int out_size, void* d_ws, size_t ws_size,
                              hipStream_t stream) {
    const float* x  = (const float*)d_in[0];
    const float* cb = (const float*)d_in[1];
    float* out = (float*)d_out;
    char* w = (char*)d_ws;

    if (ws_size >= (size_t)WS_MAIN_BYTES) {
        unsigned long long* slots = (unsigned long long*)w;
        double* accum = (double*)(w + SLOT_BYTES);
        unsigned int* counter = (unsigned int*)(w + SLOT_BYTES + 8);
        k_argmin<<<dim3(NROWS / 256, NCG), dim3(512), 0, stream>>>(
            x, cb, slots, accum, counter);
        k_final<<<dim3(NROWS / 256), dim3(256), 0, stream>>>(
            x, cb, slots, out, accum, counter);
    } else {
        float* ee = (float*)w;
        unsigned long long* packed = (unsigned long long*)(w + 65536);
        double* accum = (double*)(w + 131072);
        fb_init<<<dim3(NUM_VOCAB / 256), dim3(256), 0, stream>>>(cb, ee, packed, accum);
        fb_argmin<<<dim3(NROWS / 256, NUM_VOCAB / 1024), dim3(256), 0, stream>>>(
            x, cb, ee, packed);
        fb_final<<<dim3(NROWS / 256), dim3(256), 0, stream>>>(x, cb, packed, out, accum);
        fb_loss<<<dim3(1), dim3(1), 0, stream>>>(accum, out);
    }
}